// Round 14
// baseline (405.231 us; speedup 1.0000x reference)
//
#include <hip/hip_runtime.h>
#include <hip/hip_bf16.h>
#include <stdint.h>

#define T_TOK 4096
#define DIM   1024
#define HID   4096
#define NEXP  8
#define NSLOT (T_TOK * 2)
#define KSPLIT 2
#define KS_LEN (HID / KSPLIT)
#define MAXMT 72                 // max sum of ceil(cnt_e/128) = 8192/128 + 8
#define GRID1 (8 * 4 * MAXMT)    // 2304 gemm1 job slots
#define GRID2 (8 * 2 * MAXMT)    // 1152 gemm2 job slots
#define TP1_BLKS 512             // w1 panel-transpose: 8 e x 64 panels (64 HID-rows each)
#define TW2_BLKS 4096            // transpose w2: (HID/128)*(DIM/64)*NEXP

typedef __attribute__((ext_vector_type(8))) short bf16x8;
typedef __attribute__((ext_vector_type(4))) float f32x4;

#define AS1(p) ((const __attribute__((address_space(1))) void*)(p))
#define AS3(p) ((__attribute__((address_space(3))) void*)(p))

static __device__ __forceinline__ unsigned short f2bf(float f) {
    unsigned int u = __float_as_uint(f);
    unsigned int r = (u + 0x7fffu + ((u >> 16) & 1u)) >> 16;
    return (unsigned short)r;
}

static __device__ __forceinline__ f32x4 mfma16(bf16x8 a, bf16x8 b, f32x4 c) {
    return __builtin_amdgcn_mfma_f32_16x16x32_bf16(a, b, c, 0, 0, 0);
}

// transpose one 128x64 fp32 tile -> bf16 (kept for w2; fused into g1, hidden under gemm1)
static __device__ __forceinline__ void transpose_tile128(
    const float* __restrict__ src, unsigned short* __restrict__ dst,
    int R, int C, int e, int r0, int c0, char* smem) {
    float (*tile)[65] = (float (*)[65])smem;   // [128][65] fp32
    const int tid = threadIdx.x;
    const float* s = src + (size_t)e * R * C;
    unsigned short* d = dst + (size_t)e * C * R;
#pragma unroll
    for (int t = 0; t < 8; ++t) {
        int idx = t * 256 + tid;
        int row = idx >> 4, cq = idx & 15;
        float4 v = *(const float4*)(s + (size_t)(r0 + row) * C + c0 + cq * 4);
        tile[row][cq * 4 + 0] = v.x; tile[row][cq * 4 + 1] = v.y;
        tile[row][cq * 4 + 2] = v.z; tile[row][cq * 4 + 3] = v.w;
    }
    __syncthreads();
#pragma unroll
    for (int t = 0; t < 8; ++t) {
        int idx = t * 256 + tid;
        int c = idx >> 5, tx = idx & 31;
        ushort4 o;
        o.x = f2bf(tile[tx * 4 + 0][c]);
        o.y = f2bf(tile[tx * 4 + 1][c]);
        o.z = f2bf(tile[tx * 4 + 2][c]);
        o.w = f2bf(tile[tx * 4 + 3][c]);
        *(ushort4*)(d + (size_t)(c0 + c) * R + r0 + tx * 4) = o;
    }
}

// ---------------- fused: w1 panel-transpose (contiguous writes) + router ----------------
// Panel = 64 output rows of w1t (one e, c0..c0+63), held fully in LDS so every global
// write is a full contiguous 2KB row. Load side streams w1 columns (float4 reads);
// the transpose scatter happens in LDS where it is cheap.

__global__ __launch_bounds__(256) void pre_kernel(
    const float* __restrict__ w1, unsigned short* __restrict__ w1t,
    const float* __restrict__ x, const float* __restrict__ rw,
    const float* __restrict__ rb, unsigned short* __restrict__ xb,
    int* __restrict__ top_i, float* __restrict__ top_w, int* __restrict__ counts) {
    __shared__ unsigned short panel[64][1044];   // 133632 B; stride 2088 B (8-aligned)
    const int bid = blockIdx.x;
    if (bid < TP1_BLKS) {
        const int e = bid >> 6;          // 8 experts
        const int c0 = (bid & 63) << 6;  // 64 panels of 64 HID-rows
        const int tid = threadIdx.x;
        const float* s = w1 + (size_t)e * DIM * HID;
        // load: r = it*16 + tid>>4, cols c0 + (tid&15)*4 .. +3
        const int cq = tid & 15, rbase = tid >> 4;
#pragma unroll 4
        for (int it = 0; it < 64; ++it) {
            int r = it * 16 + rbase;
            float4 v = *(const float4*)(s + (size_t)r * HID + c0 + cq * 4);
            panel[cq * 4 + 0][r] = f2bf(v.x);
            panel[cq * 4 + 1][r] = f2bf(v.y);
            panel[cq * 4 + 2][r] = f2bf(v.z);
            panel[cq * 4 + 3][r] = f2bf(v.w);
        }
        __syncthreads();
        // store: one full 2KB output row per iteration, fully contiguous
        unsigned short* d = w1t + (size_t)e * HID * DIM;
#pragma unroll 4
        for (int cc = 0; cc < 64; ++cc) {
            ushort4 o = *(const ushort4*)&panel[cc][tid * 4];
            *(ushort4*)(d + (size_t)(c0 + cc) * DIM + tid * 4) = o;
        }
        return;
    }
    // router: one wave per token (fused x->bf16 conversion)
    int t = (bid - TP1_BLKS) * 4 + (threadIdx.x >> 6);
    int lane = threadIdx.x & 63;
    const float4* xr = (const float4*)(x + (size_t)t * DIM);
    float acc[NEXP];
#pragma unroll
    for (int e = 0; e < NEXP; ++e) acc[e] = 0.f;
#pragma unroll
    for (int i = 0; i < 4; ++i) {
        int vidx = lane + i * 64;
        float4 v = xr[vidx];
        ushort4 o;
        o.x = f2bf(v.x); o.y = f2bf(v.y); o.z = f2bf(v.z); o.w = f2bf(v.w);
        ((ushort4*)xb)[(size_t)t * 256 + vidx] = o;
        const float4* wr = (const float4*)(rw + (size_t)vidx * 4 * NEXP);
        float xs[4] = {v.x, v.y, v.z, v.w};
#pragma unroll
        for (int j = 0; j < 4; ++j) {
            float4 wlo = wr[j * 2 + 0], whi = wr[j * 2 + 1];
            acc[0] += xs[j] * wlo.x; acc[1] += xs[j] * wlo.y;
            acc[2] += xs[j] * wlo.z; acc[3] += xs[j] * wlo.w;
            acc[4] += xs[j] * whi.x; acc[5] += xs[j] * whi.y;
            acc[6] += xs[j] * whi.z; acc[7] += xs[j] * whi.w;
        }
    }
#pragma unroll
    for (int e = 0; e < NEXP; ++e) {
#pragma unroll
        for (int off = 32; off; off >>= 1) acc[e] += __shfl_xor(acc[e], off);
    }
    if (lane == 0) {
        float l[NEXP];
#pragma unroll
        for (int e = 0; e < NEXP; ++e) l[e] = acc[e] + rb[e];
        float best = -1e30f; int bi = 0;
#pragma unroll
        for (int e = 0; e < NEXP; ++e) if (l[e] > best) { best = l[e]; bi = e; }
        float best2 = -1e30f; int bi2 = 0;
#pragma unroll
        for (int e = 0; e < NEXP; ++e) { if (e == bi) continue; if (l[e] > best2) { best2 = l[e]; bi2 = e; } }
        float w0 = 1.f / (1.f + expf(best2 - best));
        top_i[t * 2] = bi;  top_i[t * 2 + 1] = bi2;
        top_w[t * 2] = w0;  top_w[t * 2 + 1] = 1.f - w0;
        atomicAdd(&counts[bi], 1);
        atomicAdd(&counts[bi2], 1);
    }
}

// tile_start[e] = cumsum of ceil(counts[e]/128); tile_start[8] = total M-tiles
__global__ void scan_kernel(const int* __restrict__ counts, int* __restrict__ offsets,
                            int* __restrict__ tile_start) {
    if (threadIdx.x == 0) {
        int o = 0, t = 0;
        for (int e = 0; e < NEXP; ++e) {
            offsets[e] = o;
            tile_start[e] = t;
            t += (counts[e] + 127) >> 7;
            o += counts[e];
        }
        tile_start[NEXP] = t;
    }
}

__global__ __launch_bounds__(256) void assign_kernel(
    const int* __restrict__ top_i, const float* __restrict__ top_w,
    const int* __restrict__ offsets, int* __restrict__ cursors,
    int* __restrict__ row_token, float* __restrict__ row_w,
    int* __restrict__ slot_of) {
    int t = blockIdx.x * 256 + threadIdx.x;
    if (t >= T_TOK) return;
#pragma unroll
    for (int k = 0; k < 2; ++k) {
        int e = top_i[t * 2 + k];
        int s = atomicAdd(&cursors[e], 1);
        int g = offsets[e] + s;
        row_token[g] = t;
        row_w[g] = top_w[t * 2 + k];
        slot_of[t * 2 + k] = g;
    }
}

// ---------------- fused: GEMM1 + transpose w2 (round-8/12 verified GEMM body) ----------------

__global__ __launch_bounds__(256, 4) void g1_kernel(
    const unsigned short* __restrict__ xb,    // [T][DIM] bf16
    const unsigned short* __restrict__ w1t,   // [E][HID][DIM] bf16
    const float* __restrict__ b1,             // [E][HID]
    const int* __restrict__ row_token, const int* __restrict__ offsets,
    const int* __restrict__ counts, const int* __restrict__ ts,
    unsigned short* __restrict__ h_ws,        // [NSLOT][HID] bf16
    const float* __restrict__ w2, unsigned short* __restrict__ w2t) {
    __shared__ __align__(16) char smem[33280];
    const int bid = blockIdx.x;
    if (bid >= GRID1) {
        // w2 [E][HID][DIM] -> w2t [E][DIM][HID]
        int r = bid - GRID1;
        int e = r >> 9;
        int rest = r & 511;
        int c0 = (rest & 15) << 6;
        int r0 = (rest >> 4) << 7;
        transpose_tile128(w2, w2t, HID, DIM, e, r0, c0, smem);
        return;
    }
    const int xcd = bid & 7, s = bid >> 3;
    if (s >= 4 * ts[NEXP]) return;
    int e = 0;
#pragma unroll
    for (int k = 1; k < NEXP; ++k) if (s >= 4 * ts[k]) e = k;
    const int ntile = ts[e + 1] - ts[e];
    const int local = s - 4 * ts[e];
    const int q = local / ntile;              // 0..3
    const int mt = local - q * ntile;
    const int nt = q * 8 + xcd;               // 0..31
    const int cnt = counts[e];
    const int goff = offsets[e];

    unsigned short (*As)[64] = (unsigned short (*)[64])smem;            // 16 KB
    unsigned short (*Bs)[64] = (unsigned short (*)[64])(smem + 16384);  // 16 KB

    const int tid = threadIdx.x, wid = tid >> 6, lane = tid & 63;
    const int wm = wid >> 1, wn = wid & 1;

    f32x4 acc[4][4];
#pragma unroll
    for (int i = 0; i < 4; ++i)
#pragma unroll
        for (int j = 0; j < 4; ++j) acc[i][j] = (f32x4){0.f, 0.f, 0.f, 0.f};

    const unsigned short* srcA[4];
    const unsigned short* srcB[4];
#pragma unroll
    for (int it = 0; it < 4; ++it) {
        int idx = it * 256 + tid;
        int r = idx >> 3, kg = idx & 7;
        int sk = kg ^ (r & 7);                 // swizzled source chunk
        int rr = mt * 128 + r;
        int tok = row_token[goff + (rr < cnt ? rr : 0)];
        srcA[it] = xb + (size_t)tok * DIM + sk * 8;
        srcB[it] = w1t + ((size_t)e * HID + nt * 128 + r) * DIM + sk * 8;
    }

    for (int t = 0; t < 16; ++t) {
        const int k0 = t * 64;
#pragma unroll
        for (int it = 0; it < 4; ++it) {
            __builtin_amdgcn_global_load_lds(AS1(srcA[it] + k0),
                AS3((char*)As + (it * 4 + wid) * 1024), 16, 0, 0);
            __builtin_amdgcn_global_load_lds(AS1(srcB[it] + k0),
                AS3((char*)Bs + (it * 4 + wid) * 1024), 16, 0, 0);
        }
        __syncthreads();                       // drains vmcnt: tile ready
#pragma unroll
        for (int kk = 0; kk < 2; ++kk) {
            bf16x8 a[4], b[4];
            int ch = (kk * 4 + (lane >> 4)) ^ (lane & 7);
#pragma unroll
            for (int i = 0; i < 4; ++i) {
                int row = wm * 64 + i * 16 + (lane & 15);
                a[i] = *(const bf16x8*)((const char*)As + row * 128 + ch * 16);
            }
#pragma unroll
            for (int i = 0; i < 4; ++i) {
                int row = wn * 64 + i * 16 + (lane & 15);
                b[i] = *(const bf16x8*)((const char*)Bs + row * 128 + ch * 16);
            }
#pragma unroll
            for (int i = 0; i < 4; ++i)
#pragma unroll
                for (int j = 0; j < 4; ++j)
                    acc[i][j] = mfma16(a[i], b[j], acc[i][j]);
        }
        __syncthreads();                       // all waves done reading before restage
    }

    if (mt * 128 + 128 <= cnt) {               // fast path: full tile
#pragma unroll
        for (int j = 0; j < 4; ++j) {
            int n = nt * 128 + wn * 64 + j * 16 + (lane & 15);
            float bias = b1[e * HID + n];
#pragma unroll
            for (int i = 0; i < 4; ++i) {
#pragma unroll
                for (int q2 = 0; q2 < 4; ++q2) {
                    int rr = mt * 128 + wm * 64 + i * 16 + (lane >> 4) * 4 + q2;
                    float v = fmaxf(acc[i][j][q2] + bias, 0.f);
                    h_ws[(size_t)(goff + rr) * HID + n] = f2bf(v);
                }
            }
        }
    } else {
#pragma unroll
        for (int j = 0; j < 4; ++j) {
            int n = nt * 128 + wn * 64 + j * 16 + (lane & 15);
            float bias = b1[e * HID + n];
#pragma unroll
            for (int i = 0; i < 4; ++i) {
#pragma unroll
                for (int q2 = 0; q2 < 4; ++q2) {
                    int rr = mt * 128 + wm * 64 + i * 16 + (lane >> 4) * 4 + q2;
                    if (rr < cnt) {
                        float v = fmaxf(acc[i][j][q2] + bias, 0.f);
                        h_ws[(size_t)(goff + rr) * HID + n] = f2bf(v);
                    }
                }
            }
        }
    }
}

// GEMM2 (split-K): y_part[ks][slot][n] = sum_{k in slice} h[slot][k] * w2t[e][n][k]
__global__ __launch_bounds__(256, 4) void gemm2_kernel(
    const unsigned short* __restrict__ h_ws,  // [NSLOT][HID] bf16
    const unsigned short* __restrict__ w2t,   // [E][DIM][HID] bf16
    const int* __restrict__ offsets, const int* __restrict__ counts,
    const int* __restrict__ ts,
    float* __restrict__ y_part) {             // [KSPLIT][NSLOT][DIM] f32
    const int bid = blockIdx.x;
    const int xcd = bid & 7, s = bid >> 3;
    if (s >= 2 * ts[NEXP]) return;
    int e = 0;
#pragma unroll
    for (int k = 1; k < NEXP; ++k) if (s >= 2 * ts[k]) e = k;
    const int ntile = ts[e + 1] - ts[e];
    const int local = s - 2 * ts[e];
    const int ks = local / ntile;             // 0..1
    const int mt = local - ks * ntile;
    const int nt = xcd;                       // 0..7
    const int cnt = counts[e];
    const int goff = offsets[e];

    __shared__ __align__(16) unsigned short As[128][64];
    __shared__ __align__(16) unsigned short Bs[128][64];

    const int tid = threadIdx.x, wid = tid >> 6, lane = tid & 63;
    const int wm = wid >> 1, wn = wid & 1;

    f32x4 acc[4][4];
#pragma unroll
    for (int i = 0; i < 4; ++i)
#pragma unroll
        for (int j = 0; j < 4; ++j) acc[i][j] = (f32x4){0.f, 0.f, 0.f, 0.f};

    const unsigned short* srcA[4];
    const unsigned short* srcB[4];
#pragma unroll
    for (int it = 0; it < 4; ++it) {
        int idx = it * 256 + tid;
        int r = idx >> 3, kg = idx & 7;
        int sk = kg ^ (r & 7);
        int rr = mt * 128 + r;
        int g = goff + (rr < cnt ? rr : 0);
        srcA[it] = h_ws + (size_t)g * HID + sk * 8;
        srcB[it] = w2t + ((size_t)e * DIM + nt * 128 + r) * HID + sk * 8;
    }

    const int kbase = ks * KS_LEN;
    for (int t = 0; t < KS_LEN / 64; ++t) {
        const int k0 = kbase + t * 64;
#pragma unroll
        for (int it = 0; it < 4; ++it) {
            __builtin_amdgcn_global_load_lds(AS1(srcA[it] + k0),
                AS3((char*)As + (it * 4 + wid) * 1024), 16, 0, 0);
            __builtin_amdgcn_global_load_lds(AS1(srcB[it] + k0),
                AS3((char*)Bs + (it * 4 + wid) * 1024), 16, 0, 0);
        }
        __syncthreads();
#pragma unroll
        for (int kk = 0; kk < 2; ++kk) {
            bf16x8 a[4], b[4];
            int ch = (kk * 4 + (lane >> 4)) ^ (lane & 7);
#pragma unroll
            for (int i = 0; i < 4; ++i) {
                int row = wm * 64 + i * 16 + (lane & 15);
                a[i] = *(const bf16x8*)((const char*)As + row * 128 + ch * 16);
            }
#pragma unroll
            for (int i = 0; i < 4; ++i) {
                int row = wn * 64 + i * 16 + (lane & 15);
                b[i] = *(const bf16x8*)((const char*)Bs + row * 128 + ch * 16);
            }
#pragma unroll
            for (int i = 0; i < 4; ++i)
#pragma unroll
                for (int j = 0; j < 4; ++j)
                    acc[i][j] = mfma16(a[i], b[j], acc[i][j]);
        }
        __syncthreads();
    }

    if (mt * 128 + 128 <= cnt) {
#pragma unroll
        for (int j = 0; j < 4; ++j) {
            int n = nt * 128 + wn * 64 + j * 16 + (lane & 15);
#pragma unroll
            for (int i = 0; i < 4; ++i) {
#pragma unroll
                for (int q2 = 0; q2 < 4; ++q2) {
                    int rr = mt * 128 + wm * 64 + i * 16 + (lane >> 4) * 4 + q2;
                    y_part[((size_t)ks * NSLOT + goff + rr) * DIM + n] = acc[i][j][q2];
                }
            }
        }
    } else {
#pragma unroll
        for (int j = 0; j < 4; ++j) {
            int n = nt * 128 + wn * 64 + j * 16 + (lane & 15);
#pragma unroll
            for (int i = 0; i < 4; ++i) {
#pragma unroll
                for (int q2 = 0; q2 < 4; ++q2) {
                    int rr = mt * 128 + wm * 64 + i * 16 + (lane >> 4) * 4 + q2;
                    if (rr < cnt) {
                        y_part[((size_t)ks * NSLOT + goff + rr) * DIM + n] = acc[i][j][q2];
                    }
                }
            }
        }
    }
}

// out[t][d] = w0*(p0[s0]+p1[s0]+b2[e0]) + w1*(p0[s1]+p1[s1]+b2[e1])
__global__ __launch_bounds__(256) void combine_kernel(
    const float* __restrict__ y_part, const int* __restrict__ slot_of,
    const int* __restrict__ top_i, const float* __restrict__ top_w,
    const float* __restrict__ b2, float* __restrict__ out) {
    int i = blockIdx.x * 256 + threadIdx.x;
    int t = i >> 8, c = i & 255;
    int s0 = slot_of[t * 2], s1 = slot_of[t * 2 + 1];
    int e0 = top_i[t * 2],  e1 = top_i[t * 2 + 1];
    float w0 = top_w[t * 2], w1 = top_w[t * 2 + 1];
    const float4* P = (const float4*)y_part;
    float4 p00 = P[(size_t)s0 * 256 + c];
    float4 p01 = P[((size_t)NSLOT + s0) * 256 + c];
    float4 p10 = P[(size_t)s1 * 256 + c];
    float4 p11 = P[((size_t)NSLOT + s1) * 256 + c];
    float4 b0 = ((const float4*)b2)[e0 * 256 + c];
    float4 b1 = ((const float4*)b2)[e1 * 256 + c];
    float4 o;
    o.x = w0 * (p00.x + p01.x + b0.x) + w1 * (p10.x + p11.x + b1.x);
    o.y = w0 * (p00.y + p01.y + b0.y) + w1 * (p10.y + p11.y + b1.y);
    o.z = w0 * (p00.z + p01.z + b0.z) + w1 * (p10.z + p11.z + b1.z);
    o.w = w0 * (p00.w + p01.w + b0.w) + w1 * (p10.w + p11.w + b1.w);
    ((float4*)out)[i] = o;
}

// ---------------- launch ----------------

extern "C" void kernel_launch(void* const* d_in, const int* in_sizes, int n_in,
                              void* d_out, int out_size, void* d_ws, size_t ws_size,
                              hipStream_t stream) {
    const float* x   = (const float*)d_in[0];
    const float* rw  = (const float*)d_in[1];
    const float* rb  = (const float*)d_in[2];
    const float* w1  = (const float*)d_in[3];
    const float* b1  = (const float*)d_in[4];
    const float* w2  = (const float*)d_in[5];
    const float* b2  = (const float*)d_in[6];
    float* out = (float*)d_out;

    char* ws = (char*)d_ws;
    size_t off = 0;
    auto alloc = [&](size_t bytes) { size_t r = off; off = (off + bytes + 255) & ~(size_t)255; return r; };
    unsigned short* xb   = (unsigned short*)(ws + alloc((size_t)T_TOK * DIM * 2));
    unsigned short* w1t  = (unsigned short*)(ws + alloc((size_t)NEXP * DIM * HID * 2));  // 64 MB
    unsigned short* w2t  = (unsigned short*)(ws + alloc((size_t)NEXP * HID * DIM * 2));  // 64 MB
    unsigned short* h_ws = (unsigned short*)(ws + alloc((size_t)NSLOT * HID * 2));       // 64 MB
    int*   top_i         = (int*)(ws + alloc((size_t)NSLOT * 4));
    float* top_w         = (float*)(ws + alloc((size_t)NSLOT * 4));
    int*   slot_of       = (int*)(ws + alloc((size_t)NSLOT * 4));
    int*   row_token     = (int*)(ws + alloc((size_t)NSLOT * 4));
    float* row_w         = (float*)(ws + alloc((size_t)NSLOT * 4));
    char*  ctrl          = ws + alloc(256);
    int* counts     = (int*)(ctrl);
    int* cursors    = (int*)(ctrl + 64);
    int* offsets    = (int*)(ctrl + 128);
    int* tile_start = (int*)(ctrl + 192);
    // y_part (2 x NSLOT x DIM f32 = 64 MB) aliases w1t: w1t is dead once g1 completes.
    float* y_part = (float*)w1t;

    hipMemsetAsync(ctrl, 0, 256, stream);

    // fused: w1 panel-transpose (contiguous writes) + router
    pre_kernel<<<TP1_BLKS + T_TOK / 4, 256, 0, stream>>>(w1, w1t, x, rw, rb, xb,
                                                         top_i, top_w, counts);
    scan_kernel<<<1, 64, 0, stream>>>(counts, offsets, tile_start);
    assign_kernel<<<T_TOK / 256, 256, 0, stream>>>(top_i, top_w, offsets, cursors,
                                                   row_token, row_w, slot_of);

    // fused: gemm1 + transpose w2 (w2t consumed only by gemm2, next launch)
    g1_kernel<<<GRID1 + TW2_BLKS, 256, 0, stream>>>(xb, w1t, b1, row_token, offsets,
                                                    counts, tile_start, h_ws, w2, w2t);
    gemm2_kernel<<<GRID2, 256, 0, stream>>>(h_ws, w2t, offsets, counts, tile_start, y_part);

    combine_kernel<<<T_TOK * 256 / 256, 256, 0, stream>>>(y_part, slot_of, top_i, top_w, b2, out);
}